// Round 2
// baseline (311.164 us; speedup 1.0000x reference)
//
#include <hip/hip_runtime.h>
#include <stdint.h>

// Problem constants (from reference)
#define N_GRAM   4
#define D_STATE  16
#define N_SLOTS  500000
#define N_BLADES 8
#define N_POS    (8 * 8192)          // batch * seq
#define FNV_OFFSET 2166136261u
#define FNV_PRIME  16777619u

// Mapping: 32 threads per position.
//   sub = tid & 31 : blade = sub>>2, d4 = sub&3 (float4 index within D_STATE=16)
// Each thread: 1 float4 gather from bank + 1 coalesced float4 store to out.
// NOTE: token_window is int32 on device (JAX x64 disabled -> .astype(jnp.int64)
// is a silent no-op; harness passes int32). 4 tokens = one int4 load.
__global__ __launch_bounds__(256) void TokenBladeBank_kernel(
    const int4* __restrict__ tok4,        // token_window int32: [pos][4]
    const float4* __restrict__ bank4,     // bank as float4: [blade][slot][4]
    float4* __restrict__ out4)            // out as float4: [pos][blade][4]
{
    const int tid = blockIdx.x * blockDim.x + threadIdx.x;
    const int pos = tid >> 5;
    const int sub = tid & 31;
    if (pos >= N_POS) return;

    const int4 t = tok4[pos];   // wave-broadcast: all 32 lanes of a position read same 16 B

    uint32_t h = FNV_OFFSET;
    h = (h ^ (uint32_t)t.x) * FNV_PRIME;
    h = (h ^ (uint32_t)t.y) * FNV_PRIME;
    h = (h ^ (uint32_t)t.z) * FNV_PRIME;
    h = (h ^ (uint32_t)t.w) * FNV_PRIME;
    const uint32_t addr = h % (uint32_t)N_SLOTS;

    const int blade = sub >> 2;
    const int d4    = sub & 3;

    // bank flat float4 index: blade * (N_SLOTS*4) + addr * 4 + d4
    const float4 v = bank4[(size_t)blade * ((size_t)N_SLOTS * 4) + (size_t)addr * 4 + d4];

    // out flat float4 index: pos * 32 + blade*4 + d4 == pos*32 + sub
    out4[(size_t)pos * 32 + sub] = v;
}

extern "C" void kernel_launch(void* const* d_in, const int* in_sizes, int n_in,
                              void* d_out, int out_size, void* d_ws, size_t ws_size,
                              hipStream_t stream) {
    const int4*   tok4  = (const int4*)d_in[0];    // int32 tokens, 4 per position
    const float4* bank4 = (const float4*)d_in[1];  // fp32 bank
    float4*       out4  = (float4*)d_out;          // fp32 out

    const int total_threads = N_POS * 32;   // 2,097,152
    const int block = 256;
    const int grid = (total_threads + block - 1) / block;  // 8192

    TokenBladeBank_kernel<<<grid, block, 0, stream>>>(tok4, bank4, out4);
}